// Round 5
// baseline (293.387 us; speedup 1.0000x reference)
//
#include <hip/hip_runtime.h>
#include <cmath>

#define D_MODEL 1536
#define N_HEADS 16
#define HEAD_DIM 96
#define SEQ 2048
#define BATCH 2
#define M_TOTAL 4096
#define N_QKV 4608
// 96^-0.5 * log2(e): fold into q so softmax exp becomes a bare v_exp_f32 (2^x)
#define QK_LOG2E 0.14724449f

typedef unsigned short ushort_t;
typedef __attribute__((ext_vector_type(8))) short bf16x8;
typedef __attribute__((ext_vector_type(4))) float f32x4;

static __device__ __forceinline__ ushort_t f2bf(float f) {
    unsigned u = __builtin_bit_cast(unsigned, f);
    u += 0x7fffu + ((u >> 16) & 1u);   // RNE
    return (ushort_t)(u >> 16);
}

static __device__ __forceinline__ unsigned pk2bf(float lo, float hi) {
#if __has_builtin(__builtin_amdgcn_cvt_pk_bf16_f32)
    auto v = __builtin_amdgcn_cvt_pk_bf16_f32(lo, hi);
    return __builtin_bit_cast(unsigned, v);
#else
    return (unsigned)f2bf(lo) | ((unsigned)f2bf(hi) << 16);
#endif
}

static __device__ __forceinline__ float fast_exp2(float x) {
#if __has_builtin(__builtin_amdgcn_exp2f)
    return __builtin_amdgcn_exp2f(x);
#else
    return __expf(x * 0.69314718056f);
#endif
}

typedef const __attribute__((address_space(1))) unsigned int* gas_t;
typedef __attribute__((address_space(3))) unsigned int* las_t;
static __device__ __forceinline__ void gld_lds16(const void* g, void* l) {
    // async global->LDS: PER-LANE global addr, LDS dest = wave-uniform base + lane*16
    __builtin_amdgcn_global_load_lds((gas_t)g, (las_t)l, 16, 0, 0);
}

#define MFMA16(a, b, c) __builtin_amdgcn_mfma_f32_16x16x32_bf16(a, b, c, 0, 0, 0)

// ---------------------------------------------------------------------------
// fp32 -> bf16 convert, 4 elems/thread
// ---------------------------------------------------------------------------
__global__ __launch_bounds__(256) void convert_f32_bf16(
    const float* __restrict__ in, ushort_t* __restrict__ out, int n)
{
    const int i = (blockIdx.x * 256 + threadIdx.x) * 4;
    if (i >= n) return;
    float4 v = *(const float4*)(in + i);
    ushort4 o;
    o.x = f2bf(v.x); o.y = f2bf(v.y); o.z = f2bf(v.z); o.w = f2bf(v.w);
    *(ushort4*)(out + i) = o;
}

// ---------------------------------------------------------------------------
// w_qkv prep: q,k rows get the leech rotation folded in (output-feature-space
// rotation within aligned 24-row groups). v rows converted as-is.
// ---------------------------------------------------------------------------
__global__ __launch_bounds__(256) void prep_wqkv(
    const float* __restrict__ W, const float* __restrict__ Kern,
    ushort_t* __restrict__ Wb)
{
    __shared__ float Kl[576];
    const int t = threadIdx.x;
    for (int i = t; i < 576; i += 256) Kl[i] = Kern[i];
    __syncthreads();
    const int g = blockIdx.y;                  // 24-row group, 0..191
    const int k = blockIdx.x * 256 + t;        // column 0..1535
    const float* src = W + (size_t)g * 24 * D_MODEL + k;
    ushort_t* dst = Wb + (size_t)g * 24 * D_MODEL + k;
    if (g < 128) {
        float in[24];
#pragma unroll
        for (int i = 0; i < 24; ++i) in[i] = src[(size_t)i * D_MODEL];
#pragma unroll
        for (int j = 0; j < 24; ++j) {
            float s = 0.f;
#pragma unroll
            for (int i = 0; i < 24; ++i) s = fmaf(in[i], Kl[i * 24 + j], s);
            dst[(size_t)j * D_MODEL] = f2bf(s);
        }
    } else {
#pragma unroll
        for (int i = 0; i < 24; ++i) dst[(size_t)i * D_MODEL] = f2bf(src[(size_t)i * D_MODEL]);
    }
}

// ---------------------------------------------------------------------------
// bf16 MFMA GEMM, C = A @ B^T. 128x128 tile, BK=64, 4 waves, 4x4 16x16/wave.
// LDS chunk-XOR swizzle (pos = chunk ^ (row&7)) applied via the gather
// addresses of global_load_lds; fragment reads land at the b128 bank floor.
// ---------------------------------------------------------------------------
__global__ __launch_bounds__(256, 4) void gemm_qkv_bf16(
    const ushort_t* __restrict__ X, const ushort_t* __restrict__ W,
    ushort_t* __restrict__ qb, ushort_t* __restrict__ kb, ushort_t* __restrict__ vtb)
{
    __shared__ ushort_t As[128 * 64];
    __shared__ ushort_t Bs[128 * 64];
    const int t = threadIdx.x;
    const int lane = t & 63, w = t >> 6;
    const int c = lane & 15, qd = lane >> 4;
    const int m0 = blockIdx.y * 128, n0 = blockIdx.x * 128;
    const int wr = (w >> 1) * 64, wc = (w & 1) * 64;
    const int lr = lane >> 3;               // row within 8-row inst span
    const int lc = (lane & 7) ^ lr;         // xor-swizzled data k-chunk
    const char* Xb = (const char*)X;
    const char* Wp = (const char*)W;
    const size_t rowb = 2 * D_MODEL;

    f32x4 acc[4][4];
#pragma unroll
    for (int i = 0; i < 4; ++i)
#pragma unroll
        for (int j = 0; j < 4; ++j) acc[i][j] = {0.f, 0.f, 0.f, 0.f};

    for (int k0 = 0; k0 < D_MODEL; k0 += 64) {
        __syncthreads();
#pragma unroll
        for (int j = 0; j < 4; ++j) {
            const int g = w * 4 + j;        // inst 0..15, covers rows g*8..g*8+7
            const int row = g * 8 + lr;
            gld_lds16(Xb + (size_t)(m0 + row) * rowb + k0 * 2 + lc * 16,
                      (char*)As + g * 1024);
            gld_lds16(Wp + (size_t)(n0 + row) * rowb + k0 * 2 + lc * 16,
                      (char*)Bs + g * 1024);
        }
        __syncthreads();
#pragma unroll
        for (int kc = 0; kc < 2; ++kc) {
            const int sx = ((kc * 4 + qd) ^ (c & 7)) * 16;
            bf16x8 af[4], bfr[4];
#pragma unroll
            for (int i = 0; i < 4; ++i)
                af[i] = *(const bf16x8*)((const char*)As + (wr + i * 16 + c) * 128 + sx);
#pragma unroll
            for (int j = 0; j < 4; ++j)
                bfr[j] = *(const bf16x8*)((const char*)Bs + (wc + j * 16 + c) * 128 + sx);
#pragma unroll
            for (int i = 0; i < 4; ++i)
#pragma unroll
                for (int j = 0; j < 4; ++j)
                    acc[i][j] = MFMA16(af[i], bfr[j], acc[i][j]);
        }
    }
    // epilogue: q/k scatter bf16 into [b][h][s][96] (q gets QK_LOG2E folded);
    // v written TRANSPOSED as V^T [b][h][d][s] with packed b64 stores.
#pragma unroll
    for (int j = 0; j < 4; ++j) {
        const int n = n0 + wc + j * 16 + c;
        const int which = n / D_MODEL;      // wave-uniform per j
        const int rem = n % D_MODEL;
        const int head = rem / HEAD_DIM;
        const int d = rem % HEAD_DIM;
        if (which < 2) {
            ushort_t* dst = which == 0 ? qb : kb;
            const float sc2 = which == 0 ? QK_LOG2E : 1.0f;
#pragma unroll
            for (int i = 0; i < 4; ++i)
#pragma unroll
                for (int r = 0; r < 4; ++r) {
                    const int m = m0 + wr + i * 16 + qd * 4 + r;
                    const int b_ = m >> 11, s_ = m & (SEQ - 1);
                    dst[((size_t)(b_ * N_HEADS + head) * SEQ + s_) * HEAD_DIM + d] =
                        f2bf(acc[i][j][r] * sc2);
                }
        } else {
            const int b_ = m0 >> 11;
            const int sb = (m0 & (SEQ - 1)) + wr + qd * 4;
            ushort_t* dstv = vtb + ((size_t)(b_ * N_HEADS + head) * HEAD_DIM + d) * SEQ;
#pragma unroll
            for (int i = 0; i < 4; ++i) {
                ushort4 o4;
                o4.x = f2bf(acc[i][j][0]); o4.y = f2bf(acc[i][j][1]);
                o4.z = f2bf(acc[i][j][2]); o4.w = f2bf(acc[i][j][3]);
                *(ushort4*)&dstv[sb + i * 16] = o4;
            }
        }
    }
}

__global__ __launch_bounds__(256, 4) void gemm_out_bf16(
    const ushort_t* __restrict__ A, const ushort_t* __restrict__ W,
    float* __restrict__ C)
{
    __shared__ ushort_t As[128 * 64];
    __shared__ ushort_t Bs[128 * 64];
    const int t = threadIdx.x;
    const int lane = t & 63, w = t >> 6;
    const int c = lane & 15, qd = lane >> 4;
    const int m0 = blockIdx.y * 128, n0 = blockIdx.x * 128;
    const int wr = (w >> 1) * 64, wc = (w & 1) * 64;
    const int lr = lane >> 3;
    const int lc = (lane & 7) ^ lr;
    const char* Ab = (const char*)A;
    const char* Wp = (const char*)W;
    const size_t rowb = 2 * D_MODEL;

    f32x4 acc[4][4];
#pragma unroll
    for (int i = 0; i < 4; ++i)
#pragma unroll
        for (int j = 0; j < 4; ++j) acc[i][j] = {0.f, 0.f, 0.f, 0.f};

    for (int k0 = 0; k0 < D_MODEL; k0 += 64) {
        __syncthreads();
#pragma unroll
        for (int j = 0; j < 4; ++j) {
            const int g = w * 4 + j;
            const int row = g * 8 + lr;
            gld_lds16(Ab + (size_t)(m0 + row) * rowb + k0 * 2 + lc * 16,
                      (char*)As + g * 1024);
            gld_lds16(Wp + (size_t)(n0 + row) * rowb + k0 * 2 + lc * 16,
                      (char*)Bs + g * 1024);
        }
        __syncthreads();
#pragma unroll
        for (int kc = 0; kc < 2; ++kc) {
            const int sx = ((kc * 4 + qd) ^ (c & 7)) * 16;
            bf16x8 af[4], bfr[4];
#pragma unroll
            for (int i = 0; i < 4; ++i)
                af[i] = *(const bf16x8*)((const char*)As + (wr + i * 16 + c) * 128 + sx);
#pragma unroll
            for (int j = 0; j < 4; ++j)
                bfr[j] = *(const bf16x8*)((const char*)Bs + (wc + j * 16 + c) * 128 + sx);
#pragma unroll
            for (int i = 0; i < 4; ++i)
#pragma unroll
                for (int j = 0; j < 4; ++j)
                    acc[i][j] = MFMA16(af[i], bfr[j], acc[i][j]);
        }
    }
#pragma unroll
    for (int i = 0; i < 4; ++i)
#pragma unroll
        for (int j = 0; j < 4; ++j)
#pragma unroll
            for (int r = 0; r < 4; ++r)
                C[(size_t)(m0 + wr + i * 16 + qd * 4 + r) * D_MODEL + n0 + wc + j * 16 + c] =
                    acc[i][j][r];
}

// ---------------------------------------------------------------------------
// MFMA flash attention v5: no-max softmax; S^T formulation; DOUBLE-BUFFERED
// K/Vt staging (one barrier per iter; the vmcnt drain at the barrier refers
// to loads issued a full iteration earlier -> near-zero stall).
// Block = 128 q x one (b,h); 4 waves x 32 q. BK=64 keys/iter.
//   S^T = K·Q^T  (A=K rows from chunk-major LDS, B=Q regs)
//   p = 2^s; l via in-reg sum + 2 shuffles
//   P packed to per-wave LDS [q][k] (pad 72) as b64 writes (no barrier)
//   O^T = V^T·P^T (A=Vt rows from xor-swizzled LDS, B=Ps rows)
// LDS: 2*12K (Ks) + 2*12K (Vt) + 18K (Ps) = 67.6 KB -> 2 blocks/CU, grid 512
// = exactly 2 blocks/CU (no tail).
// ---------------------------------------------------------------------------
__global__ __launch_bounds__(256, 2) void flash_bf16(
    const ushort_t* __restrict__ Q, const ushort_t* __restrict__ K,
    const ushort_t* __restrict__ VT, ushort_t* __restrict__ attn)
{
    __shared__ ushort_t Ks[2][12 * 64 * 8];  // chunk-major: (d-chunk, key, 8)
    __shared__ ushort_t Vt[2][96 * 64];      // [d][key], xor-swizzled 16B chunks
    __shared__ ushort_t Ps[4][32 * 72];      // per-wave [q][k], pad 64->72

    const int t = threadIdx.x;
    const int lane = t & 63, w = t >> 6;
    const int c = lane & 15, qd = lane >> 4;
    const int lr = lane >> 3;             // staging row-in-8
    const int lc = (lane & 7) ^ lr;       // xor-swizzled data chunk
    const int h = blockIdx.y, bb = blockIdx.z;
    const int q0 = blockIdx.x * 128;
    const size_t base = ((size_t)(bb * N_HEADS + h)) * SEQ * HEAD_DIM;
    const ushort_t* Qb = Q + base;
    const char* Kb = (const char*)(K + base);
    const ushort_t* VTb = VT + base;      // [96][2048] within (b,h)

    // Q B-operand fragments (resident all kernel): B[n=q][k=d]
    bf16x8 aq[2][3];
#pragma unroll
    for (int qi = 0; qi < 2; ++qi)
#pragma unroll
        for (int kc = 0; kc < 3; ++kc)
            aq[qi][kc] = *(const bf16x8*)(Qb +
                (size_t)(q0 + w * 32 + qi * 16 + c) * HEAD_DIM + kc * 32 + qd * 8);

    f32x4 oacc[6][2];
#pragma unroll
    for (int jd = 0; jd < 6; ++jd)
#pragma unroll
        for (int qi = 0; qi < 2; ++qi) oacc[jd][qi] = {0.f, 0.f, 0.f, 0.f};
    float lrow[2] = {0.f, 0.f};

    // staging issue helper (wave-level): K chunk-gather + Vt swizzled rows
    const int g0 = w * 3;
#define ISSUE_STAGE(buf, ktv)                                                   \
    {                                                                           \
        const char* kp = Kb + (size_t)(ktv) * 64 * 192;                         \
        _Pragma("unroll")                                                       \
        for (int jj = 0; jj < 3; ++jj) {                                        \
            const int g = g0 + jj;                                              \
            gld_lds16(kp + (size_t)lane * 192 + g * 16, (char*)Ks[buf] + g * 1024); \
        }                                                                       \
        _Pragma("unroll")                                                       \
        for (int jj = 0; jj < 3; ++jj) {                                        \
            const int g = g0 + jj;                                              \
            const int d = g * 8 + lr;                                           \
            gld_lds16((const char*)(VTb + (size_t)d * SEQ + (ktv) * 64 + lc * 8), \
                      (char*)Vt[buf] + g * 1024);                               \
        }                                                                       \
    }

    ISSUE_STAGE(0, 0)

    for (int kt = 0; kt < SEQ / 64; ++kt) {
        const int cur = kt & 1;
        __syncthreads();  // drains buf[cur] loads (issued 1 iter ago); also
                          // guarantees prior iter's readers of buf[cur^1] done
        if (kt + 1 < SEQ / 64) ISSUE_STAGE(cur ^ 1, kt + 1)

        // S^T = K Q^T : 4 key-tiles x 2 q-tiles x 3 d-chunks
        f32x4 sacc[4][2];
#pragma unroll
        for (int kti = 0; kti < 4; ++kti)
#pragma unroll
            for (int qi = 0; qi < 2; ++qi) sacc[kti][qi] = {0.f, 0.f, 0.f, 0.f};
#pragma unroll
        for (int kc = 0; kc < 3; ++kc) {
            bf16x8 ak[4];
#pragma unroll
            for (int kti = 0; kti < 4; ++kti)
                ak[kti] = *(const bf16x8*)&Ks[cur][((kc * 4 + qd) * 64 + kti * 16 + c) * 8];
#pragma unroll
            for (int kti = 0; kti < 4; ++kti)
#pragma unroll
                for (int qi = 0; qi < 2; ++qi)
                    sacc[kti][qi] = MFMA16(ak[kti], aq[qi][kc], sacc[kti][qi]);
        }

        // p = 2^s; pack b64 to Ps[q][k]; per-thread partial l
        float ls0 = 0.f, ls1 = 0.f;
#pragma unroll
        for (int kti = 0; kti < 4; ++kti)
#pragma unroll
            for (int qi = 0; qi < 2; ++qi) {
                const float p0 = fast_exp2(sacc[kti][qi][0]);
                const float p1 = fast_exp2(sacc[kti][qi][1]);
                const float p2 = fast_exp2(sacc[kti][qi][2]);
                const float p3 = fast_exp2(sacc[kti][qi][3]);
                uint2 pk;
                pk.x = pk2bf(p0, p1);
                pk.y = pk2bf(p2, p3);
                *(uint2*)&Ps[w][(qi * 16 + c) * 72 + kti * 16 + qd * 4] = pk;
                const float s = (p0 + p1) + (p2 + p3);
                if (qi == 0) ls0 += s; else ls1 += s;
            }
        ls0 += __shfl_xor(ls0, 16, 64); ls0 += __shfl_xor(ls0, 32, 64);
        ls1 += __shfl_xor(ls1, 16, 64); ls1 += __shfl_xor(ls1, 32, 64);
        lrow[0] += ls0; lrow[1] += ls1;

        // O^T += V^T P^T : 6 d-tiles x 2 q-tiles x 2 k-chunks (intra-wave Ps)
#pragma unroll
        for (int kc = 0; kc < 2; ++kc) {
            bf16x8 bp[2];
#pragma unroll
            for (int qi = 0; qi < 2; ++qi)
                bp[qi] = *(const bf16x8*)&Ps[w][(qi * 16 + c) * 72 + kc * 32 + qd * 8];
#pragma unroll
            for (int jd = 0; jd < 6; ++jd) {
                const int sx = ((kc * 4 + qd) ^ (c & 7)) * 16;
                const bf16x8 av =
                    *(const bf16x8*)((const char*)Vt[cur] + (jd * 16 + c) * 128 + sx);
#pragma unroll
                for (int qi = 0; qi < 2; ++qi)
                    oacc[jd][qi] = MFMA16(av, bp[qi], oacc[jd][qi]);
            }
        }
    }
#undef ISSUE_STAGE

    // epilogue: O^T C-layout (col=q=c, row=d=qd*4+r); attn[b][s][h*96+d] bf16
#pragma unroll
    for (int qi = 0; qi < 2; ++qi) {
        const float linv = 1.0f / lrow[qi];
        const int row = bb * SEQ + q0 + w * 32 + qi * 16 + c;
        ushort_t* dst = attn + (size_t)row * D_MODEL + h * HEAD_DIM + qd * 4;
#pragma unroll
        for (int jd = 0; jd < 6; ++jd) {
            ushort4 o4;
            o4.x = f2bf(oacc[jd][qi][0] * linv);
            o4.y = f2bf(oacc[jd][qi][1] * linv);
            o4.z = f2bf(oacc[jd][qi][2] * linv);
            o4.w = f2bf(oacc[jd][qi][3] * linv);
            *(ushort4*)(dst + jd * 16) = o4;
        }
    }
}

// ---------------------------------------------------------------------------

extern "C" void kernel_launch(void* const* d_in, const int* in_sizes, int n_in,
                              void* d_out, int out_size, void* d_ws, size_t ws_size,
                              hipStream_t stream)
{
    const float* x     = (const float*)d_in[0];
    const float* w_qkv = (const float*)d_in[1];
    const float* w_out = (const float*)d_in[2];
    const float* leech = (const float*)d_in[3];
    float* out = (float*)d_out;
    char* ws = (char*)d_ws;

    ushort_t* xb    = (ushort_t*)(ws);                 // 12582912 B
    ushort_t* wqkvb = (ushort_t*)(ws + 12582912);      // 14155776 B
    ushort_t* woutb = (ushort_t*)(ws + 26738688);      //  4718592 B
    ushort_t* qb    = (ushort_t*)(ws + 31457280);      // 12582912 B each
    ushort_t* kb    = (ushort_t*)(ws + 44040192);
    ushort_t* vtb   = (ushort_t*)(ws + 56623104);      // V^T [b][h][96][2048]
    ushort_t* attnb = (ushort_t*)(ws + 69206016);      // ends 81788928

    convert_f32_bf16<<<6144, 256, 0, stream>>>(x, xb, M_TOTAL * D_MODEL);
    prep_wqkv<<<dim3(6, 192), 256, 0, stream>>>(w_qkv, leech, wqkvb);
    convert_f32_bf16<<<2304, 256, 0, stream>>>(w_out, woutb, D_MODEL * D_MODEL);

    gemm_qkv_bf16<<<dim3(N_QKV / 128, M_TOTAL / 128), 256, 0, stream>>>(
        xb, wqkvb, qb, kb, vtb);

    flash_bf16<<<dim3(SEQ / 128, N_HEADS, BATCH), 256, 0, stream>>>(
        qb, kb, vtb, attnb);

    gemm_out_bf16<<<dim3(D_MODEL / 128, M_TOTAL / 128), 256, 0, stream>>>(
        attnb, woutb, out);
}